// Round 10
// baseline (36927.618 us; speedup 1.0000x reference)
//
#include <hip/hip_runtime.h>

#define Bn 128
#define Tn 1024
#define INn 256
#define Hn 512
#define NB 256   // persistent blocks (1 per CU), 1024 threads each

typedef short bf16x8 __attribute__((ext_vector_type(8)));
typedef float f32x4 __attribute__((ext_vector_type(4)));

// ---- ws layout (bytes) ----
#define WHI_OFF  0u
#define WLO_OFF  11534336u
#define BIAS_OFF 23068672u
#define H_OFF    23093248u   // f32 h[3][2][128][512]   (sys/MALL-coherent)
#define STG_OFF  24666112u   // f32 stg[8][3][128][512] (per-XCD L2-local copies)
#define H3F_OFF  30957568u   // f32 [128][512]
#define BAR_OFF  31219712u   // 8KB barrier/membership area

__device__ __forceinline__ float sigm(float x) { return 1.0f / (1.0f + __expf(-x)); }
__device__ __forceinline__ unsigned short bf_hi(float x) {
  unsigned u = __builtin_bit_cast(unsigned, x);
  return (unsigned short)(u >> 16);
}
__device__ __forceinline__ float bf_f(unsigned short h) {
  unsigned u = ((unsigned)h) << 16;
  return __builtin_bit_cast(float, u);
}

// Pack fp32 weights into MFMA-fragment-ordered bf16 hi/lo arrays.
// dst elem offset = layer_base + (((jt*2+ns)*NCH + kc)*64 + lane)*8
// col n = ns*16+(lane&15) -> gate row r = (n>>3)*512 + jt*8 + (n&7),
// k0 = kc*32 + (lane>>4)*8 over concat [x ; h]  (same (lane,e)->k map as A-frags).
__global__ void pack_weights(const float* __restrict__ wih1, const float* __restrict__ whh1,
                             const float* __restrict__ wih2, const float* __restrict__ whh2,
                             const float* __restrict__ wih3, const float* __restrict__ whh3,
                             unsigned short* __restrict__ whi, unsigned short* __restrict__ wlo) {
  int gid = blockIdx.x * 256 + threadIdx.x;
  int rem, NCH, kih; size_t base; const float *wih, *whh;
  if (gid < 196608)      { rem = gid;          base = 0;       NCH = 24; kih = 256; wih = wih1; whh = whh1; }
  else if (gid < 458752) { rem = gid - 196608; base = 1572864; NCH = 32; kih = 512; wih = wih2; whh = whh2; }
  else if (gid < 720896) { rem = gid - 458752; base = 3670016; NCH = 32; kih = 512; wih = wih3; whh = whh3; }
  else return;
  const int lane = rem & 63; rem >>= 6;
  const int kc = rem % NCH; rem /= NCH;
  const int ns = rem & 1;
  const int jt = rem >> 1;
  const int n = ns * 16 + (lane & 15);
  const int g = n >> 3, jl = n & 7;
  const int r = g * 512 + jt * 8 + jl;
  const int k0 = kc * 32 + (lane >> 4) * 8;
  const float* src = (k0 < kih) ? (wih + (size_t)r * kih + k0)
                                : (whh + (size_t)r * 512 + (k0 - kih));
  size_t dst = base + ((((size_t)jt * 2 + ns) * NCH + kc) * 64 + lane) * 8;
#pragma unroll
  for (int e = 0; e < 8; ++e) {
    float w = src[e];
    unsigned short h = bf_hi(w);
    whi[dst + e] = h;
    wlo[dst + e] = bf_hi(w - bf_f(h));
  }
}

__global__ void pack_bias(const float* __restrict__ bi1, const float* __restrict__ bh1,
                          const float* __restrict__ bi2, const float* __restrict__ bh2,
                          const float* __restrict__ bi3, const float* __restrict__ bh3,
                          float* __restrict__ bias) {
  int gid = blockIdx.x * 256 + threadIdx.x;
  if (gid >= 6144) return;
  int l = gid >> 11, r = gid & 2047;
  const float* bi = (l == 0) ? bi1 : (l == 1) ? bi2 : bi3;
  const float* bh = (l == 0) ? bh1 : (l == 1) ? bh2 : bh3;
  bias[gid] = bi[r] + bh[r];
}

// Grid barrier, ALL RELAXED (r9-proven: no L2 invalidation, weights stay
// resident). Counter-sharding by bid&7 (exact 32 per group, mapping-agnostic).
__device__ __forceinline__ void gridbar(unsigned* bar, unsigned idx, int shard) {
  __syncthreads();
  if (threadIdx.x == 0) {
    asm volatile("" ::: "memory");
    unsigned* xc   = bar + shard * 32;
    unsigned* root = bar + 256;
    unsigned* ep   = bar + 288;
    unsigned o = __hip_atomic_fetch_add(xc, 1u, __ATOMIC_RELAXED, __HIP_MEMORY_SCOPE_AGENT);
    if (o == idx * 32u - 1u) {
      unsigned r = __hip_atomic_fetch_add(root, 1u, __ATOMIC_RELAXED, __HIP_MEMORY_SCOPE_AGENT);
      if (r == idx * 8u - 1u)
        __hip_atomic_store(ep, idx, __ATOMIC_RELAXED, __HIP_MEMORY_SCOPE_AGENT);
    }
    while (__hip_atomic_load(ep, __ATOMIC_RELAXED, __HIP_MEMORY_SCOPE_AGENT) < idx)
      __builtin_amdgcn_s_sleep(1);
    asm volatile("" ::: "memory");
  }
  __syncthreads();
}

// Persistent fused LSTM: 256 blocks x 1024 threads.
// Per phase: (1) stage h[rp] (sys-reads, once per XCD) into this XCD's
// L2-local buffer; (2) XCD-local count-barrier (real XCC_ID, dynamic
// membership); (3) compute with A from staged L2 copy (agent loads bypass
// L1), B from L2-resident packed weights; h[wp] written via system stores.
__global__ __launch_bounds__(1024, 4) void lstm_persist(
    const float* __restrict__ embed,
    const unsigned short* __restrict__ whi,
    const unsigned short* __restrict__ wlo,
    const float* __restrict__ bias,
    float* __restrict__ hsys,          // [3][2][128][512] f32, MALL-coherent
    float* __restrict__ stg,           // [8][3][128][512] f32, per-XCD local
    float* __restrict__ h3f,
    unsigned* __restrict__ bar)
{
  const int bid = blockIdx.x;
  const int shard = bid & 7;
  const int idx = bid >> 3;           // 0..31
  const int jt  = shard * 8 + (idx & 7);
  const int bt  = idx >> 3;           // 0..3
  const int j0  = jt * 8;
  const int b0  = bt * 32;
  const int tid = (int)threadIdx.x;
  const int lane = tid & 63;
  const int w = tid >> 6;             // 0..15
  const int bsub = w & 1, kq = w >> 1;            // kq 0..7

  __shared__ float pre[2][8][32][36];   // [parity][kq][brow][gatecol]
  __shared__ float sbias[3][32];
  __shared__ int s_xcd, s_slot, s_nx;

  if (tid == 0) {
    unsigned x;
    asm volatile("s_getreg_b32 %0, hwreg(HW_REG_XCC_ID)" : "=s"(x));
    s_xcd = (int)(x & 7u);
  }
  if (tid < 96) {
    int l = tid >> 5, n = tid & 31;
    sbias[l][n] = bias[l * 2048 + (n >> 3) * 512 + j0 + (n & 7)];
  }
  __syncthreads();
  const int myxcd = s_xcd;
  // register membership in my (real) XCD group
  if (tid == 0)
    s_slot = (int)__hip_atomic_fetch_add(bar + 1024 + myxcd * 16, 1u,
                                         __ATOMIC_RELAXED, __HIP_MEMORY_SCOPE_AGENT);
  // zero h state via SYSTEM stores (MALL-coherent, deterministic per launch)
  unsigned long long* hs_u = (unsigned long long*)hsys;
  for (int i = bid * 1024 + tid; i < 196608; i += NB * 1024)
    __hip_atomic_store(hs_u + i, 0ull, __ATOMIC_RELAXED, __HIP_MEMORY_SCOPE_SYSTEM);

  float c0 = 0.f, c1 = 0.f, c2 = 0.f;   // cell state for (b0+bloc, j0+jl), tid<256
  unsigned bidx = 1;
  gridbar(bar, bidx++, shard);          // membership + h-init now frozen/visible
  if (tid == 0)
    s_nx = (int)__hip_atomic_load(bar + 1024 + myxcd * 16,
                                  __ATOMIC_RELAXED, __HIP_MEMORY_SCOPE_AGENT);
  __syncthreads();
  const int slot = s_slot, nx = s_nx;

  unsigned long long* stg_u = (unsigned long long*)stg;
  const int arow = b0 + bsub * 16 + (lane & 15);   // A-frag b row
  const int kgrp = (lane >> 4) * 8;                // k-offset in 32-chunk
  const int bloc = (tid >> 3) & 31, jl = tid & 7;  // cell-update mapping (tid<256)

  for (int p = 0; p <= 1024; ++p) {
    const int rp = (p + 1) & 1, wp = p & 1;

    // ---- stage h[rp] -> this XCD's L2-local copy (once per XCD) ----
    for (int u = slot * 1024 + tid; u < 98304; u += nx * 1024) {
      const int li = u >> 15, rem = u & 32767;
      unsigned long long v = __hip_atomic_load(hs_u + (size_t)(li * 2 + rp) * 32768 + rem,
                                               __ATOMIC_RELAXED, __HIP_MEMORY_SCOPE_SYSTEM);
      stg_u[(size_t)myxcd * 98304 + (size_t)li * 32768 + rem] = v;   // plain -> local L2
    }
    __syncthreads();                    // drain stage stores to L2
    if (tid == 0) {
      __hip_atomic_fetch_add(bar + 512 + myxcd * 64, 1u,
                             __ATOMIC_RELAXED, __HIP_MEMORY_SCOPE_AGENT);
      const unsigned tgt = (unsigned)nx * (unsigned)(p + 1);
      while (__hip_atomic_load(bar + 512 + myxcd * 64,
                               __ATOMIC_RELAXED, __HIP_MEMORY_SCOPE_AGENT) < tgt)
        __builtin_amdgcn_s_sleep(1);
      asm volatile("" ::: "memory");
    }
    __syncthreads();

#pragma unroll
    for (int l = 0; l < 3; ++l) {
      const int t = p - l;
      if (t >= 0 && t <= 1022) {
        const int NCH = (l == 0) ? 24 : 32;
        const int eighth = NCH >> 3;                 // 3 or 4
        const size_t wbase = (l == 0) ? 0u : ((l == 1) ? 1572864u : 3670016u);
        const unsigned short* wh0 = whi + wbase + ((size_t)(jt * 2 + 0) * NCH) * 512 + lane * 8;
        const unsigned short* wl0 = wlo + wbase + ((size_t)(jt * 2 + 0) * NCH) * 512 + lane * 8;
        const unsigned short* wh1 = whi + wbase + ((size_t)(jt * 2 + 1) * NCH) * 512 + lane * 8;
        const unsigned short* wl1 = wlo + wbase + ((size_t)(jt * 2 + 1) * NCH) * 512 + lane * 8;

        f32x4 acc0 = {0.f,0.f,0.f,0.f}, acc1 = {0.f,0.f,0.f,0.f};
        const int kc0 = kq * eighth;

#pragma unroll
        for (int i = 0; i < 4; ++i) {
          if (i >= eighth) break;                    // compile-time per l
          const int kc = kc0 + i;
          const int k0 = kc * 32 + kgrp;
          float xs[8];
          if (l == 0 && kc < 8) {                    // embed fp32 (plain cached)
            const float* s = embed + ((size_t)arow * Tn + t) * INn + k0;
            const f32x4 x0 = *reinterpret_cast<const f32x4*>(s);
            const f32x4 x1 = *reinterpret_cast<const f32x4*>(s + 4);
            xs[0]=x0.x; xs[1]=x0.y; xs[2]=x0.z; xs[3]=x0.w;
            xs[4]=x1.x; xs[5]=x1.y; xs[6]=x1.z; xs[7]=x1.w;
          } else {                                   // h from XCD-local stage (agent: skip L1, hit L2)
            int srcl, off;
            if (l == 0)           { srcl = 0;     off = k0 - 256; }
            else if (k0 < 512)    { srcl = l - 1; off = k0;       }
            else                  { srcl = l;     off = k0 - 512; }
            const unsigned long long* sp = stg_u + (size_t)myxcd * 98304
                                         + (size_t)srcl * 32768
                                         + (((size_t)arow * 512 + off) >> 1);
#pragma unroll
            for (int q = 0; q < 4; ++q) {
              unsigned long long v = __hip_atomic_load(sp + q, __ATOMIC_RELAXED,
                                                       __HIP_MEMORY_SCOPE_AGENT);
              xs[2*q]   = __builtin_bit_cast(float, (unsigned)(v & 0xffffffffu));
              xs[2*q+1] = __builtin_bit_cast(float, (unsigned)(v >> 32));
            }
          }
          bf16x8 aH, aL;
#pragma unroll
          for (int e = 0; e < 8; ++e) {
            unsigned short h1 = bf_hi(xs[e]);
            aH[e] = (short)h1;
            aL[e] = (short)bf_hi(xs[e] - bf_f(h1));
          }
          const bf16x8 bH0 = *reinterpret_cast<const bf16x8*>(wh0 + (size_t)kc * 512);
          const bf16x8 bL0 = *reinterpret_cast<const bf16x8*>(wl0 + (size_t)kc * 512);
          const bf16x8 bH1 = *reinterpret_cast<const bf16x8*>(wh1 + (size_t)kc * 512);
          const bf16x8 bL1 = *reinterpret_cast<const bf16x8*>(wl1 + (size_t)kc * 512);
          acc0 = __builtin_amdgcn_mfma_f32_16x16x32_bf16(aH, bH0, acc0, 0, 0, 0);
          acc0 = __builtin_amdgcn_mfma_f32_16x16x32_bf16(aL, bH0, acc0, 0, 0, 0);
          acc0 = __builtin_amdgcn_mfma_f32_16x16x32_bf16(aH, bL0, acc0, 0, 0, 0);
          acc0 = __builtin_amdgcn_mfma_f32_16x16x32_bf16(aL, bL0, acc0, 0, 0, 0);
          acc1 = __builtin_amdgcn_mfma_f32_16x16x32_bf16(aH, bH1, acc1, 0, 0, 0);
          acc1 = __builtin_amdgcn_mfma_f32_16x16x32_bf16(aL, bH1, acc1, 0, 0, 0);
          acc1 = __builtin_amdgcn_mfma_f32_16x16x32_bf16(aH, bL1, acc1, 0, 0, 0);
          acc1 = __builtin_amdgcn_mfma_f32_16x16x32_bf16(aL, bL1, acc1, 0, 0, 0);
        }

        const int pb = l & 1;  // l0/l2 share plane 0: separated by l1's __syncthreads
        {
          const int prow = bsub * 16 + ((lane >> 4) << 2);
          const int pc = lane & 15;
#pragma unroll
          for (int r = 0; r < 4; ++r) {
            pre[pb][kq][prow + r][pc]      = acc0[r];
            pre[pb][kq][prow + r][16 + pc] = acc1[r];
          }
        }
        __syncthreads();
        if (tid < 256) {
          float g0 = sbias[l][jl],      g1 = sbias[l][8 + jl];
          float g2 = sbias[l][16 + jl], g3 = sbias[l][24 + jl];
#pragma unroll
          for (int q = 0; q < 8; ++q) {
            g0 += pre[pb][q][bloc][jl];
            g1 += pre[pb][q][bloc][8 + jl];
            g2 += pre[pb][q][bloc][16 + jl];
            g3 += pre[pb][q][bloc][24 + jl];
          }
          const float ig = sigm(g0), fg = sigm(g1), gg = tanhf(g2), og = sigm(g3);
          float& c = (l == 0) ? c0 : ((l == 1) ? c1 : c2);
          c = fg * c + ig * gg;
          const float hv = og * tanhf(c);
          const size_t hi = (size_t)(l * 2 + wp) * 65536 + (size_t)(b0 + bloc) * 512 + (j0 + jl);
          __hip_atomic_store((unsigned*)hsys + hi, __builtin_bit_cast(unsigned, hv),
                             __ATOMIC_RELAXED, __HIP_MEMORY_SCOPE_SYSTEM);
          if (l == 2 && t == 1022)
            h3f[(size_t)(b0 + bloc) * Hn + (j0 + jl)] = hv;
        }
      }
    }
    gridbar(bar, bidx++, shard);
  }
}

// FC epilogue: out2[b][o] = h3_final[b,:] . fc_w[o,:] + fc_b[o]
__global__ void fc_kernel(const float* __restrict__ h3f, const float* __restrict__ fcw,
                          const float* __restrict__ fcb, float* __restrict__ out) {
  const int gid = blockIdx.x * 256 + (int)threadIdx.x;
  if (gid >= Bn * INn) return;
  const int b = gid >> 8, o = gid & 255;
  const float* hr = h3f + (size_t)b * Hn;
  const float* wr = fcw + (size_t)o * Hn;
  float acc = fcb[o];
#pragma unroll 4
  for (int k = 0; k < Hn; k += 4) {
    const float4 hv = *reinterpret_cast<const float4*>(hr + k);
    const float4 wv = *reinterpret_cast<const float4*>(wr + k);
    acc = fmaf(hv.x, wv.x, acc); acc = fmaf(hv.y, wv.y, acc);
    acc = fmaf(hv.z, wv.z, acc); acc = fmaf(hv.w, wv.w, acc);
  }
  out[(size_t)Bn * Tn * INn + gid] = acc;
}

extern "C" void kernel_launch(void* const* d_in, const int* in_sizes, int n_in,
                              void* d_out, int out_size, void* d_ws, size_t ws_size,
                              hipStream_t stream) {
  const float* embed = (const float*)d_in[0];
  const float* wih1  = (const float*)d_in[1];
  const float* whh1  = (const float*)d_in[2];
  const float* bih1  = (const float*)d_in[3];
  const float* bhh1  = (const float*)d_in[4];
  const float* wih2  = (const float*)d_in[5];
  const float* whh2  = (const float*)d_in[6];
  const float* bih2  = (const float*)d_in[7];
  const float* bhh2  = (const float*)d_in[8];
  const float* wih3  = (const float*)d_in[9];
  const float* whh3  = (const float*)d_in[10];
  const float* bih3  = (const float*)d_in[11];
  const float* bhh3  = (const float*)d_in[12];
  const float* fcw   = (const float*)d_in[13];
  const float* fcb   = (const float*)d_in[14];
  float* outp = (float*)d_out;

  char* ws = (char*)d_ws;
  unsigned short* whi = (unsigned short*)(ws + WHI_OFF);
  unsigned short* wlo = (unsigned short*)(ws + WLO_OFF);
  float* bias         = (float*)(ws + BIAS_OFF);
  float* hsys         = (float*)(ws + H_OFF);
  float* stg          = (float*)(ws + STG_OFF);
  float* h3f          = (float*)(ws + H3F_OFF);
  unsigned* bar       = (unsigned*)(ws + BAR_OFF);

  // Output 0: embed passthrough (128 MB d2d)
  hipMemcpyAsync(d_out, d_in[0], (size_t)Bn * Tn * INn * sizeof(float),
                 hipMemcpyDeviceToDevice, stream);
  // barrier/membership counters must start at 0 every launch
  hipMemsetAsync(bar, 0, 8192, stream);

  pack_weights<<<2816, 256, 0, stream>>>(wih1, whh1, wih2, whh2, wih3, whh3, whi, wlo);
  pack_bias<<<24, 256, 0, stream>>>(bih1, bhh1, bih2, bhh2, bih3, bhh3, bias);

  void* args[] = { (void*)&embed, (void*)&whi, (void*)&wlo, (void*)&bias,
                   (void*)&hsys, (void*)&stg, (void*)&h3f, (void*)&bar };
  dim3 grid(NB), block(1024);
  hipLaunchCooperativeKernel((const void*)lstm_persist, grid, block, args, 0, stream);

  fc_kernel<<<128, 256, 0, stream>>>(h3f, fcw, fcb, outp);
}